// Round 4
// baseline (851.195 us; speedup 1.0000x reference)
//
#include <hip/hip_runtime.h>

// out[i] = x[i] - max(ceil(x[i]), 1.0f)
// Pure streaming elementwise: HBM-bound (1.074 GB traffic, ~170 us at 6.3 TB/s achievable).
// Strategy:
//  - float4 (16 B/lane) coalesced access
//  - capped grid-stride loop (2048 blocks = 256 CU x 8 wg/CU) so waves stay resident
//  - non-temporal load/store: 1 GB stream is 4x the 256 MiB L3, zero reuse -> bypass allocation
//  - 2-deep unroll: two independent in-flight loads per iteration for HBM latency hiding

typedef float f32x4 __attribute__((ext_vector_type(4)));

__device__ __forceinline__ f32x4 recur4(f32x4 v) {
    f32x4 r;
    r.x = v.x - fmaxf(ceilf(v.x), 1.0f);
    r.y = v.y - fmaxf(ceilf(v.y), 1.0f);
    r.z = v.z - fmaxf(ceilf(v.z), 1.0f);
    r.w = v.w - fmaxf(ceilf(v.w), 1.0f);
    return r;
}

__global__ __launch_bounds__(256) void recur_kernel_vec4_gs(const f32x4* __restrict__ x,
                                                            f32x4* __restrict__ out,
                                                            int n4) {
    const int stride = gridDim.x * blockDim.x;
    int i = blockIdx.x * blockDim.x + threadIdx.x;
    // 2-deep unrolled grid-stride: issue both loads before either store.
    for (; i + stride < n4; i += 2 * stride) {
        f32x4 v0 = __builtin_nontemporal_load(&x[i]);
        f32x4 v1 = __builtin_nontemporal_load(&x[i + stride]);
        f32x4 r0 = recur4(v0);
        f32x4 r1 = recur4(v1);
        __builtin_nontemporal_store(r0, &out[i]);
        __builtin_nontemporal_store(r1, &out[i + stride]);
    }
    if (i < n4) {
        f32x4 v = __builtin_nontemporal_load(&x[i]);
        __builtin_nontemporal_store(recur4(v), &out[i]);
    }
}

// Tail kernel in case n % 4 != 0 (not expected here: n = 2^27).
__global__ __launch_bounds__(64) void recur_kernel_tail(const float* __restrict__ x,
                                                        float* __restrict__ out,
                                                        int start, int n) {
    int i = start + blockIdx.x * blockDim.x + threadIdx.x;
    if (i < n) {
        float v = x[i];
        out[i] = v - fmaxf(ceilf(v), 1.0f);
    }
}

extern "C" void kernel_launch(void* const* d_in, const int* in_sizes, int n_in,
                              void* d_out, int out_size, void* d_ws, size_t ws_size,
                              hipStream_t stream) {
    const float* x = (const float*)d_in[0];
    float* out = (float*)d_out;
    int n = in_sizes[0];

    int n4 = n / 4;
    if (n4 > 0) {
        const int threads = 256;
        // 256 CUs x 8 workgroups/CU = 2048 blocks; grid-stride covers the rest.
        int blocks = (n4 + threads - 1) / threads;
        if (blocks > 2048) blocks = 2048;
        recur_kernel_vec4_gs<<<blocks, threads, 0, stream>>>(
            (const f32x4*)x, (f32x4*)out, n4);
    }
    int rem = n - n4 * 4;
    if (rem > 0) {
        recur_kernel_tail<<<1, 64, 0, stream>>>(x, out, n4 * 4, n);
    }
}